// Round 1
// baseline (460.979 us; speedup 1.0000x reference)
//
#include <hip/hip_runtime.h>
#include <cstddef>
#include <cstdint>

// ---------------------------------------------------------------------------
// MultiHeadSelfAttention: x(4,2048,1024) fp32, W(3072,1024) fp32, Wo(1024,1024)
// Pipeline: cvt->bf16 | GEMM1 qkv | RoPE(Q,K) | transpose V | flash attn | GEMM2
// All MFMA bf16 16x16x32, fp32 accum.
// ---------------------------------------------------------------------------

typedef unsigned short u16;
typedef short bf16x8 __attribute__((ext_vector_type(8)));   // 8 bf16 = 4 VGPRs
typedef float f32x4 __attribute__((ext_vector_type(4)));

#define B_   4
#define L_   2048
#define H_   16
#define DH_  64
#define D_   1024
#define E3_  3072

__device__ __forceinline__ u16 f2bf(float f) {            // RNE f32 -> bf16
  unsigned int u = __float_as_uint(f);
  u += 0x7fffu + ((u >> 16) & 1u);
  return (u16)(u >> 16);
}
__device__ __forceinline__ float bf2f(u16 h) {
  return __uint_as_float(((unsigned int)h) << 16);
}

// ---------------------------------------------------------------- cvt fp32->bf16
__global__ __launch_bounds__(256) void cvt_bf16(const float* __restrict__ in,
                                                u16* __restrict__ out, int n8) {
  int i = blockIdx.x * 256 + threadIdx.x;
  if (i >= n8) return;
  const float4* p = (const float4*)in;
  float4 a = p[2 * i], b = p[2 * i + 1];
  uint4 o;
  o.x = (unsigned)f2bf(a.x) | ((unsigned)f2bf(a.y) << 16);
  o.y = (unsigned)f2bf(a.z) | ((unsigned)f2bf(a.w) << 16);
  o.z = (unsigned)f2bf(b.x) | ((unsigned)f2bf(b.y) << 16);
  o.w = (unsigned)f2bf(b.z) | ((unsigned)f2bf(b.w) << 16);
  ((uint4*)out)[i] = o;
}

// ---------------------------------------------------------------- GEMM C = A * B^T
// A: MxK bf16 row-major, Bm: NxK bf16 row-major, C: MxN (bf16 or fp32)
// 128x128 block tile, 4 waves (2x2 of 64x64), BK=32.
template <bool OUT_BF16>
__global__ __launch_bounds__(256) void gemm_bt(const u16* __restrict__ A,
                                               const u16* __restrict__ Bm,
                                               void* __restrict__ C, int N, int K) {
  __shared__ __align__(16) u16 As[128 * 40];   // stride 40 elems (80B) kills conflicts
  __shared__ __align__(16) u16 Bs[128 * 40];
  const int tid = threadIdx.x;
  const int lane = tid & 63, wave = tid >> 6;
  const int quad = lane >> 4, l15 = lane & 15;
  const int wm = (wave >> 1) << 6, wn = (wave & 1) << 6;
  const int m0 = blockIdx.y << 7, n0 = blockIdx.x << 7;

  f32x4 acc[4][4];
#pragma unroll
  for (int i = 0; i < 4; ++i)
#pragma unroll
    for (int j = 0; j < 4; ++j) acc[i][j] = {0.f, 0.f, 0.f, 0.f};

  const int r0 = tid >> 2;            // staging row 0..63 (+64)
  const int c0 = (tid & 3) * 8;       // staging col chunk

  for (int k0 = 0; k0 < K; k0 += 32) {
#pragma unroll
    for (int it = 0; it < 2; ++it) {
      int row = r0 + it * 64;
      *(uint4*)(As + row * 40 + c0) =
          *(const uint4*)(A + (size_t)(m0 + row) * K + k0 + c0);
      *(uint4*)(Bs + row * 40 + c0) =
          *(const uint4*)(Bm + (size_t)(n0 + row) * K + k0 + c0);
    }
    __syncthreads();
    bf16x8 af[4], bfr[4];
#pragma unroll
    for (int i = 0; i < 4; ++i)
      af[i] = *(const bf16x8*)(As + (wm + i * 16 + l15) * 40 + quad * 8);
#pragma unroll
    for (int j = 0; j < 4; ++j)
      bfr[j] = *(const bf16x8*)(Bs + (wn + j * 16 + l15) * 40 + quad * 8);
#pragma unroll
    for (int i = 0; i < 4; ++i)
#pragma unroll
      for (int j = 0; j < 4; ++j)
        acc[i][j] = __builtin_amdgcn_mfma_f32_16x16x32_bf16(af[i], bfr[j],
                                                            acc[i][j], 0, 0, 0);
    __syncthreads();
  }
  // epilogue: C/D layout col=lane&15, row=quad*4+reg
#pragma unroll
  for (int i = 0; i < 4; ++i) {
    int row = m0 + wm + i * 16 + quad * 4;
#pragma unroll
    for (int j = 0; j < 4; ++j) {
      int col = n0 + wn + j * 16 + l15;
#pragma unroll
      for (int r = 0; r < 4; ++r) {
        if (OUT_BF16)
          ((u16*)C)[(size_t)(row + r) * N + col] = f2bf(acc[i][j][r]);
        else
          ((float*)C)[(size_t)(row + r) * N + col] = acc[i][j][r];
      }
    }
  }
}

// ---------------------------------------------------------------- RoPE on Q,K (in place, bf16)
// One thread per (b,l,t<2,h,pair). Q additionally scaled by 0.125*log2(e)
// so attention can use exp2 with the scale pre-folded.
__global__ __launch_bounds__(256) void rope_qk(u16* __restrict__ qkvb) {
  int i = blockIdx.x * 256 + threadIdx.x;   // 8,388,608 threads
  int d2 = i & 31;
  int h  = (i >> 5) & 15;
  int t  = (i >> 9) & 1;
  int bl = i >> 10;                          // b*L + l, 0..8191
  int l  = bl & (L_ - 1);
  size_t off = (size_t)bl * E3_ + t * D_ + h * DH_ + d2 * 2;
  // inv_freq = theta^(-d2/32) = 2^(-d2 * log2(1e5)/32)
  float inv = exp2f((float)d2 * -0.5190512648261504f);
  float ang = (float)l * inv;
  float sn, cs;
  sincosf(ang, &sn, &cs);
  float x1 = bf2f(qkvb[off]), x2 = bf2f(qkvb[off + 1]);
  float o1 = x1 * cs - x2 * sn;
  float o2 = x2 * cs + x1 * sn;
  if (t == 0) { o1 *= 0.18033688011112042f; o2 *= 0.18033688011112042f; }
  qkvb[off]     = f2bf(o1);
  qkvb[off + 1] = f2bf(o2);
}

// ---------------------------------------------------------------- V transpose: (b,l,h,d)->(b,h,d,l)
__global__ __launch_bounds__(256) void transpose_v(const u16* __restrict__ qkvb,
                                                   u16* __restrict__ Vt) {
  __shared__ u16 tile[64 * 65];
  const int bh = blockIdx.x, b = bh >> 4, h = bh & 15;
  const int lbase = blockIdx.y << 6;
  const int tid = threadIdx.x;
#pragma unroll
  for (int i = 0; i < 16; ++i) {
    int flat = i * 256 + tid;
    int l = flat >> 6, d = flat & 63;
    tile[l * 65 + d] =
        qkvb[(size_t)(b * L_ + lbase + l) * E3_ + 2 * D_ + h * DH_ + d];
  }
  __syncthreads();
#pragma unroll
  for (int i = 0; i < 16; ++i) {
    int flat = i * 256 + tid;
    int d = flat >> 6, l = flat & 63;
    Vt[(size_t)(bh * DH_ + d) * L_ + lbase + l] = tile[l * 65 + d];
  }
}

// ---------------------------------------------------------------- flash attention (causal)
// grid (L/64, B*H), block 256 = 4 waves; each wave owns 16 query rows.
// Q pre-scaled by 0.125*log2e -> exp2 softmax.
__global__ __launch_bounds__(256) void attn(const u16* __restrict__ qkvb,
                                            const u16* __restrict__ Vt,
                                            u16* __restrict__ Ob) {
  __shared__ __align__(16) u16 Ks[64 * 72];     // [key][d]
  __shared__ __align__(16) u16 Vs[64 * 72];     // [d][key]
  __shared__ __align__(16) u16 Ps[4 * 16 * 72]; // per-wave P tile [q][key]
  const int bh = blockIdx.y, b = bh >> 4, h = bh & 15;
  const int qbase = blockIdx.x << 6;
  const int tid = threadIdx.x;
  const int lane = tid & 63, wave = tid >> 6, quad = lane >> 4, l15 = lane & 15;

  // Q fragments stay in registers the whole kernel (A-layout: m=l15, k=quad*8+j)
  const int qrow = qbase + wave * 16 + l15;
  const u16* qptr = qkvb + (size_t)(b * L_ + qrow) * E3_ + h * DH_;
  bf16x8 qf0 = *(const bf16x8*)(qptr + quad * 8);
  bf16x8 qf1 = *(const bf16x8*)(qptr + 32 + quad * 8);

  float m_run[4], l_run[4];
  f32x4 acc[4];
#pragma unroll
  for (int r = 0; r < 4; ++r) { m_run[r] = -__builtin_inff(); l_run[r] = 0.f; }
#pragma unroll
  for (int j = 0; j < 4; ++j) acc[j] = {0.f, 0.f, 0.f, 0.f};

  const int qrow_c = qbase + wave * 16 + quad * 4;  // C-layout row base
  const int r0 = tid >> 3, c0 = (tid & 7) * 8;      // staging map: 64 rows x 8 chunks
  u16* pw = Ps + wave * (16 * 72);

  for (int kb = 0; kb <= qbase; kb += 64) {
    __syncthreads();   // protect Ks/Vs from previous iteration's MFMA reads
#pragma unroll
    for (int it = 0; it < 2; ++it) {
      int row = r0 + it * 32;
      *(uint4*)(Ks + row * 72 + c0) = *(const uint4*)(
          qkvb + (size_t)(b * L_ + kb + row) * E3_ + D_ + h * DH_ + c0);
      *(uint4*)(Vs + row * 72 + c0) =
          *(const uint4*)(Vt + (size_t)(bh * DH_ + row) * L_ + kb + c0);
    }
    __syncthreads();

    // S = Q K^T  (s[t]: keys t*16..t*16+15)
    f32x4 s[4];
#pragma unroll
    for (int t = 0; t < 4; ++t) s[t] = {0.f, 0.f, 0.f, 0.f};
#pragma unroll
    for (int ks = 0; ks < 2; ++ks) {
      bf16x8 qf = ks ? qf1 : qf0;
#pragma unroll
      for (int t = 0; t < 4; ++t) {
        bf16x8 kf =
            *(const bf16x8*)(Ks + (t * 16 + l15) * 72 + ks * 32 + quad * 8);
        s[t] = __builtin_amdgcn_mfma_f32_16x16x32_bf16(qf, kf, s[t], 0, 0, 0);
      }
    }
    // causal mask: only the diagonal k-tile needs it
    if (kb == qbase) {
#pragma unroll
      for (int t = 0; t < 4; ++t) {
        int kg = kb + t * 16 + l15;
#pragma unroll
        for (int r = 0; r < 4; ++r)
          if (kg > qrow_c + r) s[t][r] = -__builtin_inff();
      }
    }
    // online softmax (exp2 domain; scale folded into Q)
    float alpha[4];
#pragma unroll
    for (int r = 0; r < 4; ++r) {
      float mx = fmaxf(fmaxf(s[0][r], s[1][r]), fmaxf(s[2][r], s[3][r]));
      mx = fmaxf(mx, __shfl_xor(mx, 1));
      mx = fmaxf(mx, __shfl_xor(mx, 2));
      mx = fmaxf(mx, __shfl_xor(mx, 4));
      mx = fmaxf(mx, __shfl_xor(mx, 8));
      float mn = fmaxf(m_run[r], mx);
      alpha[r] = exp2f(m_run[r] - mn);      // exp2(-inf)=0 on first tile
      m_run[r] = mn;
      float rs = 0.f;
#pragma unroll
      for (int t = 0; t < 4; ++t) {
        float p = exp2f(s[t][r] - mn);
        s[t][r] = p;
        rs += p;
      }
      rs += __shfl_xor(rs, 1);
      rs += __shfl_xor(rs, 2);
      rs += __shfl_xor(rs, 4);
      rs += __shfl_xor(rs, 8);
      l_run[r] = l_run[r] * alpha[r] + rs;
    }
#pragma unroll
    for (int j = 0; j < 4; ++j)
#pragma unroll
      for (int r = 0; r < 4; ++r) acc[j][r] *= alpha[r];

    // P: C-layout -> LDS -> A-layout (per-wave region, stride 72 breaks conflicts)
#pragma unroll
    for (int t = 0; t < 4; ++t)
#pragma unroll
      for (int r = 0; r < 4; ++r)
        pw[(quad * 4 + r) * 72 + t * 16 + l15] = f2bf(s[t][r]);
    __threadfence_block();   // order same-wave LDS write -> read

    // O += P * V   (B-frag from Vs[d][key]: contiguous along key)
#pragma unroll
    for (int ks = 0; ks < 2; ++ks) {
      bf16x8 pf = *(const bf16x8*)(pw + l15 * 72 + ks * 32 + quad * 8);
#pragma unroll
      for (int j = 0; j < 4; ++j) {
        bf16x8 vf =
            *(const bf16x8*)(Vs + (j * 16 + l15) * 72 + ks * 32 + quad * 8);
        acc[j] = __builtin_amdgcn_mfma_f32_16x16x32_bf16(pf, vf, acc[j], 0, 0, 0);
      }
    }
  }

  // epilogue: normalize, LDS round-trip for coalesced bf16 store to (b,l,h*64+d)
  __syncthreads();
  u16* Os = Ks;  // reuse
#pragma unroll
  for (int j = 0; j < 4; ++j)
#pragma unroll
    for (int r = 0; r < 4; ++r) {
      float o = acc[j][r] / l_run[r];
      Os[(wave * 16 + quad * 4 + r) * 72 + j * 16 + l15] = f2bf(o);
    }
  __syncthreads();
#pragma unroll
  for (int it = 0; it < 2; ++it) {
    int row = r0 + it * 32;
    *(uint4*)(Ob + (size_t)(b * L_ + qbase + row) * D_ + h * DH_ + c0) =
        *(const uint4*)(Os + row * 72 + c0);
  }
}

// ---------------------------------------------------------------- launch
extern "C" void kernel_launch(void* const* d_in, const int* in_sizes, int n_in,
                              void* d_out, int out_size, void* d_ws, size_t ws_size,
                              hipStream_t stream) {
  const float* x  = (const float*)d_in[0];
  const float* W  = (const float*)d_in[1];
  const float* Wo = (const float*)d_in[2];
  float* out = (float*)d_out;

  // workspace layout (bytes): total ~104 MB
  char* ws = (char*)d_ws;
  u16* xb   = (u16*)(ws);                    // 16,777,216
  u16* Wb   = (u16*)(ws + 16777216);         //  6,291,456
  u16* Wob  = (u16*)(ws + 23068672);         //  2,097,152
  u16* qkvb = (u16*)(ws + 25165824);         // 50,331,648  (B,L,3,H,DH) bf16
  u16* Vt   = (u16*)(ws + 75497472);         // 16,777,216  (B,H,DH,L) bf16
  u16* Ob   = (u16*)(ws + 92274688);         // 16,777,216  (B,L,D) bf16

  cvt_bf16<<<4096, 256, 0, stream>>>(x, xb, 1048576);
  cvt_bf16<<<1536, 256, 0, stream>>>(W, Wb, 393216);
  cvt_bf16<<<512, 256, 0, stream>>>(Wo, Wob, 131072);

  gemm_bt<true><<<dim3(E3_ / 128, (B_ * L_) / 128), 256, 0, stream>>>(
      xb, Wb, qkvb, E3_, D_);

  rope_qk<<<32768, 256, 0, stream>>>(qkvb);
  transpose_v<<<dim3(B_ * H_, L_ / 64), 256, 0, stream>>>(qkvb, Vt);

  attn<<<dim3(L_ / 64, B_ * H_), 256, 0, stream>>>(qkvb, Vt, Ob);

  gemm_bt<false><<<dim3(D_ / 128, (B_ * L_) / 128), 256, 0, stream>>>(
      Ob, Wob, out, D_, D_);
}